// Round 7
// baseline (257.322 us; speedup 1.0000x reference)
//
#include <hip/hip_runtime.h>
#include <hip/hip_fp16.h>
#include <stdint.h>

#define O_FEAT 4096
#define I_FEAT 4096
#define M_DIM  2048
#define K_DIM  4096

typedef __attribute__((ext_vector_type(8))) short short8;   // 8 x bf16 (4 VGPRs)
typedef __attribute__((ext_vector_type(2))) short short2v;  // 2 x bf16 (1 VGPR)
typedef __attribute__((ext_vector_type(4))) float floatx4;  // MFMA accumulator

#define AS1 __attribute__((address_space(1)))
#define AS3 __attribute__((address_space(3)))

__device__ __forceinline__ uint16_t f32_to_bf16(float f) {
    uint32_t u = __builtin_bit_cast(uint32_t, f);
    u = (u + 0x7FFFu + ((u >> 16) & 1u)) >> 16;   // round-to-nearest-even
    return (uint16_t)u;
}
__device__ __forceinline__ float bf16_to_f32(uint16_t h) {
    uint32_t u = ((uint32_t)h) << 16;
    return __builtin_bit_cast(float, u);
}

// async global->LDS, 16B per lane; LDS dest = wave-uniform base + lane*16
__device__ __forceinline__ void load_lds16(const uint16_t* gptr, uint16_t* ldsptr) {
    __builtin_amdgcn_global_load_lds((const AS1 uint32_t*)gptr,
                                     (AS3 uint32_t*)ldsptr, 16, 0, 0);
}

// ---------------------------------------------------------------------------
// Kernel 1 (fused): blocks [0,8192) dequant int4 -> bf16 W;
//                   blocks [8192,12288) convert x fp32 -> bf16 Xb.
// Probe-adaptive packed format (uint8 raw vs int32-widened).
// ---------------------------------------------------------------------------
__global__ __launch_bounds__(256) void prep_kernel(
        const void*  __restrict__ packed,
        const float* __restrict__ scales,
        const float* __restrict__ x,
        uint16_t*    __restrict__ W,
        uint16_t*    __restrict__ Xb) {
    if (blockIdx.x < 8192) {
        const int lane = threadIdx.x & 63;
        uint32_t probe = ((const uint32_t*)packed)[lane];
        const bool int32mode = (__ballot(probe >= 256u) == 0ull);

        int idx = blockIdx.x * 256 + threadIdx.x;       // 2,097,152 threads
        float s = scales[idx >> 9];                     // 512 byte-quads per row

        uint32_t bytes4;
        if (int32mode) {
            uint4 w = ((const uint4*)packed)[idx];      // 4 int32, each 0..255
            bytes4 = (w.x & 0xFFu) | ((w.y & 0xFFu) << 8) |
                     ((w.z & 0xFFu) << 16) | ((w.w & 0xFFu) << 24);
        } else {
            bytes4 = ((const uint32_t*)packed)[idx];
        }

        uint16_t o[8];
#pragma unroll
        for (int b = 0; b < 4; ++b) {
            int byte = (bytes4 >> (8 * b)) & 0xFF;
            o[2 * b]     = f32_to_bf16((float)((byte & 0xF) - 8) * s);  // low -> even
            o[2 * b + 1] = f32_to_bf16((float)((byte >> 4) - 8) * s);   // high -> odd
        }
        uint4 v;
        v.x = (uint32_t)o[0] | ((uint32_t)o[1] << 16);
        v.y = (uint32_t)o[2] | ((uint32_t)o[3] << 16);
        v.z = (uint32_t)o[4] | ((uint32_t)o[5] << 16);
        v.w = (uint32_t)o[6] | ((uint32_t)o[7] << 16);
        ((uint4*)W)[idx] = v;
    } else {
        int idx = (blockIdx.x - 8192) * 256 + threadIdx.x;   // 1,048,576 threads
        float4 v0 = ((const float4*)x)[2 * idx];
        float4 v1 = ((const float4*)x)[2 * idx + 1];
        uint4 o;
        o.x = (uint32_t)f32_to_bf16(v0.x) | ((uint32_t)f32_to_bf16(v0.y) << 16);
        o.y = (uint32_t)f32_to_bf16(v0.z) | ((uint32_t)f32_to_bf16(v0.w) << 16);
        o.z = (uint32_t)f32_to_bf16(v1.x) | ((uint32_t)f32_to_bf16(v1.y) << 16);
        o.w = (uint32_t)f32_to_bf16(v1.z) | ((uint32_t)f32_to_bf16(v1.w) << 16);
        ((uint4*)Xb)[idx] = o;
    }
}

// ---------------------------------------------------------------------------
// Kernel 2: scatter-add COO residual into bf16 W via packed-bf16 HW atomic
// (CAS fallback).  Probe-adaptive fp16/fp32 vals format.
// ---------------------------------------------------------------------------
__global__ __launch_bounds__(256) void scatter_kernel(
        const void* __restrict__ vals,
        const int*  __restrict__ rows,
        const int*  __restrict__ cols,
        const float* __restrict__ alpha,
        uint16_t*   __restrict__ W,
        int nnz) {
    const int lane = threadIdx.x & 63;
    float p = fabsf(((const float*)vals)[lane]);
    int cnt = __popcll(__ballot(p > 1e-4f && p < 1.0f));
    const bool f32mode = (cnt >= 32);

    int i = blockIdx.x * 256 + threadIdx.x;
    if (i >= nnz) return;
    float v = f32mode ? ((const float*)vals)[i]
                      : __half2float(((const __half*)vals)[i]);
    v *= alpha[0];
    int r = rows[i], c = cols[i];
    size_t elem = (size_t)r * I_FEAT + c;

#if __has_builtin(__builtin_amdgcn_global_atomic_fadd_v2bf16)
    const bool hi = (elem & 1);
    short b = (short)f32_to_bf16(v);
    short2v val;
    val[0] = hi ? (short)0 : b;
    val[1] = hi ? b : (short)0;
    __builtin_amdgcn_global_atomic_fadd_v2bf16(
        (AS1 short2v*)(W + (elem & ~(size_t)1)), val);
#else
    uint32_t* word = (uint32_t*)W + (elem >> 1);
    bool hi = (c & 1);
    uint32_t old = *word, assumed;
    do {
        assumed = old;
        uint16_t cur = hi ? (uint16_t)(assumed >> 16) : (uint16_t)(assumed & 0xFFFF);
        uint16_t nw  = f32_to_bf16(bf16_to_f32(cur) + v);
        uint32_t neww = hi ? ((assumed & 0x0000FFFFu) | ((uint32_t)nw << 16))
                           : ((assumed & 0xFFFF0000u) | (uint32_t)nw);
        old = atomicCAS(word, assumed, neww);
    } while (old != assumed);
#endif
}

// ---------------------------------------------------------------------------
// Kernel 3: C[M,N] = A[M,K] * B[N,K]^T  (bf16 in, fp32 out).
// R7 change: 64x128 tile (was 128x128) -> 1024 blocks = 4 blocks/CU for
// latency overlap (R5/R6 showed 60% idle at 2 blocks/CU, grid-limited).
// BK=32, 2x2 waves (each 32x64), 16x16x32 MFMA, async global_load_lds.
// LDS 12 KB, acc 2x4 per wave.
// ---------------------------------------------------------------------------
__global__ __launch_bounds__(256, 4) void gemm_bt_kernel(
        const uint16_t* __restrict__ A,   // [2048][4096] bf16
        const uint16_t* __restrict__ B,   // [4096][4096] bf16 (row-major [N][K])
        float* __restrict__ C) {          // [2048][4096] fp32
    __shared__ uint16_t As[64 * 32];      // 4 KB
    __shared__ uint16_t Bs[128 * 32];     // 8 KB

    const int tid  = threadIdx.x;
    const int wave = tid >> 6;
    const int lane = tid & 63;
    const int wm = wave >> 1, wn = wave & 1;   // 2x2 wave grid: 32 M x 64 N each
    const int bm0 = blockIdx.y * 64;
    const int bn0 = blockIdx.x * 128;

    // staging: one chunk = 16 rows x 32 elems = 1024 B = one wave-load
    // (lane -> row lane>>2, 16B seg (lane&3)*8).  A: 4 chunks, B: 8 chunks.
    // wave w loads A-chunk w, B-chunks w and w+4.
    const int lrow = lane >> 2;          // 0..15
    const int lcol = (lane & 3) * 8;     // elem offset within 32-wide K slab

    floatx4 acc[2][4];
#pragma unroll
    for (int i = 0; i < 2; ++i)
#pragma unroll
        for (int j = 0; j < 4; ++j) acc[i][j] = {0.f, 0.f, 0.f, 0.f};

    const int fr = lane & 15;            // fragment row within 16
    const int ko = (lane >> 4) * 8;      // fragment k offset

    const uint16_t* aP  = A + (size_t)(bm0 + wave * 16 + lrow) * K_DIM + lcol;
    const uint16_t* bP0 = B + (size_t)(bn0 + wave * 16 + lrow) * K_DIM + lcol;
    const uint16_t* bP1 = B + (size_t)(bn0 + (wave + 4) * 16 + lrow) * K_DIM + lcol;
    uint16_t* aL  = &As[wave * 512];
    uint16_t* bL0 = &Bs[wave * 512];
    uint16_t* bL1 = &Bs[(wave + 4) * 512];

    for (int k0 = 0; k0 < K_DIM; k0 += 32) {
        __syncthreads();                 // prior LDS reads done before overwrite
        load_lds16(aP + k0, aL);
        load_lds16(bP0 + k0, bL0);
        load_lds16(bP1 + k0, bL1);
        __syncthreads();                 // drains vmcnt for global_load_lds

        short8 af[2], bf[4];
#pragma unroll
        for (int i = 0; i < 2; ++i)
            af[i] = *(const short8*)&As[(wm * 32 + i * 16 + fr) * 32 + ko];
#pragma unroll
        for (int j = 0; j < 4; ++j)
            bf[j] = *(const short8*)&Bs[(wn * 64 + j * 16 + fr) * 32 + ko];
#pragma unroll
        for (int i = 0; i < 2; ++i)
#pragma unroll
            for (int j = 0; j < 4; ++j)
                acc[i][j] = __builtin_amdgcn_mfma_f32_16x16x32_bf16(
                    af[i], bf[j], acc[i][j], 0, 0, 0);
    }

    // epilogue: C/D layout col=lane&15, row=(lane>>4)*4+reg   [m89/m91]
    const int cn = lane & 15;
    const int rb = (lane >> 4) * 4;
#pragma unroll
    for (int i = 0; i < 2; ++i)
#pragma unroll
        for (int j = 0; j < 4; ++j)
#pragma unroll
            for (int r = 0; r < 4; ++r) {
                const int row = bm0 + wm * 32 + i * 16 + rb + r;
                const int col = bn0 + wn * 64 + j * 16 + cn;
                C[(size_t)row * O_FEAT + col] = acc[i][j][r];
            }
}

// ---------------------------------------------------------------------------
extern "C" void kernel_launch(void* const* d_in, const int* in_sizes, int n_in,
                              void* d_out, int out_size, void* d_ws, size_t ws_size,
                              hipStream_t stream) {
    const float* x      = (const float*)d_in[0];
    const void*  packed = d_in[1];
    const float* scales = (const float*)d_in[2];
    const void*  vals   = d_in[3];
    const int*   rows   = (const int*)d_in[4];
    const int*   cols   = (const int*)d_in[5];
    const float* alpha  = (const float*)d_in[6];
    float*       out    = (float*)d_out;
    const int nnz = in_sizes[3];

    uint16_t* W  = (uint16_t*)d_ws;                                        // 32 MB
    uint16_t* Xb = (uint16_t*)((char*)d_ws + (size_t)O_FEAT * I_FEAT * 2); // 16 MB

    // 1) fused dequant (blocks 0..8191) + x conversion (blocks 8192..12287)
    prep_kernel<<<12288, 256, 0, stream>>>(packed, scales, x, W, Xb);
    // 2) scatter sparse residual into W (packed bf16 hardware atomics)
    scatter_kernel<<<(nnz + 255) / 256, 256, 0, stream>>>(vals, rows, cols, alpha, W, nnz);
    // 3) GEMM: out = Xb (2048x4096) * W^T (4096x4096), 64x128 tiles
    gemm_bt_kernel<<<dim3(O_FEAT / 128, M_DIM / 64), 256, 0, stream>>>(Xb, W, out);
}